// Round 11
// baseline (1305.282 us; speedup 1.0000x reference)
//
#include <hip/hip_runtime.h>

// BiLSTM-CRF on MI355X — round 11: pair-split lstm_scan (2 CUs per sequence).
// 256 blocks (= all CUs; 80KB+ LDS forces 1 block/CU so all pairs co-resident
// by construction). Block (d,b,p) owns j in [p*128,(p+1)*128): weights fully
// resident (40 kk LDS slab + 22x uint4 regs/thread = 128 kk, ZERO per-step
// weight stream). Per-step h-halves (256 B) exchanged via agent-scope atomic
// dwords + release flag; flags memset to -1 on stream each call (deterministic,
// graph-captured). Double-buffered slots; producer overwrites a parity slot
// only after partner flag >= s-1 (already required to read partner h).
//
// ws: X4 67108864 | WTH 1048576 | FT 786432 | WpH 12288 | H 16777216 |
//     slots 131072 | flags 1024   = 85.87 MB.
// Output (float32): d_out[0:16384] = paths (floats, -1 past length), [16384:16448] = best_score.

#define NB 64
#define NT 256
#define NKTAG 12
#define START_TAG 10

typedef unsigned short u16;
typedef _Float16 half2v __attribute__((ext_vector_type(2)));
typedef _Float16 half8 __attribute__((ext_vector_type(8)));
typedef float f32x4 __attribute__((ext_vector_type(4)));

__device__ __forceinline__ float b2f(u16 u) {
  union { unsigned int i; float f; } v; v.i = ((unsigned int)u) << 16; return v.f;
}
__device__ __forceinline__ u16 f2b(float f) {
  union { float f; unsigned int i; } v; v.f = f;
  unsigned int r = v.i + 0x7FFFu + ((v.i >> 16) & 1u);
  return (u16)(r >> 16);
}
__device__ __forceinline__ u16 f2h(float f) {
  union { _Float16 h; u16 u; } v; v.h = (_Float16)f; return v.u;
}
__device__ __forceinline__ unsigned int pkh(float x, float y) {
  return (unsigned int)f2h(x) | ((unsigned int)f2h(y) << 16);
}
__device__ __forceinline__ float fsig(float x) { return 1.0f / (1.0f + __expf(-x)); }
__device__ __forceinline__ float ftanh(float x) { return 2.0f / (1.0f + __expf(-2.0f * x)) - 1.0f; }

__device__ __forceinline__ float dot2h(unsigned int a, unsigned int b, float c) {
#if __has_builtin(__builtin_amdgcn_fdot2)
  union { unsigned int u; half2v h; } va, vb;
  va.u = a; vb.u = b;
  return __builtin_amdgcn_fdot2(va.h, vb.h, c, false);
#else
  float d;
  asm("v_dot2_f32_f16 %0, %1, %2, %3" : "=v"(d) : "v"(a), "v"(b), "v"(c));
  return d;
#endif
}

// ---------------------------------------------------------------- pack_whh (+WpH)
__global__ __launch_bounds__(256) void pack_whh(const float* __restrict__ Whf,
                                                const float* __restrict__ Whb,
                                                const float* __restrict__ Wp,
                                                uint4* __restrict__ WT,
                                                unsigned int* __restrict__ WpH) {
  if (blockIdx.x == 256) {   // WpH: [12][256] packed f16 pairs of Wp[12][512]
    for (int it = 0; it < 12; ++it) {
      int idx = it * 256 + threadIdx.x;
      int k = idx >> 8, cc = idx & 255;
      WpH[idx] = pkh(Wp[(size_t)k * 512 + 2 * cc], Wp[(size_t)k * 512 + 2 * cc + 1]);
    }
    return;
  }
  int gid = blockIdx.x * 256 + threadIdx.x;      // 2*128*256 = 65536
  int d = gid >> 15;
  int rem = gid & 32767;
  int kk = rem >> 8, j = rem & 255;
  const float* W = d ? Whb : Whf;
  int k0 = kk * 2;
  uint4 o;
  o.x = pkh(W[(size_t)j * 256 + k0],         W[(size_t)j * 256 + k0 + 1]);
  o.y = pkh(W[(size_t)(j + 256) * 256 + k0], W[(size_t)(j + 256) * 256 + k0 + 1]);
  o.z = pkh(W[(size_t)(j + 512) * 256 + k0], W[(size_t)(j + 512) * 256 + k0 + 1]);
  o.w = pkh(W[(size_t)(j + 768) * 256 + k0], W[(size_t)(j + 768) * 256 + k0 + 1]);
  WT[gid] = o;
}

// ---------------------------------------------------------------- gemm_x (MFMA)
// (unchanged from round 10)
__global__ __launch_bounds__(256) void gemm_x(const int* __restrict__ sent,
                                              const float* __restrict__ emb,
                                              const float* __restrict__ Wf,
                                              const float* __restrict__ Wb,
                                              const float* __restrict__ bihf,
                                              const float* __restrict__ bhhf,
                                              const float* __restrict__ bihb,
                                              const float* __restrict__ bhhb,
                                              u16* __restrict__ X4) {
  __shared__ _Float16 A_lds[128][40];
  __shared__ _Float16 B_lds[64][40];
  __shared__ int tok[128];
  __shared__ u16 Xs[128][80];
  int tid = threadIdx.x;
  int in = blockIdx.x;                 // 0..31
  int im = blockIdx.y;                 // 0..127
  int d = in >> 4, j0 = (in & 15) * 16;
  if (tid < 128) tok[tid] = sent[im * 128 + tid];

  int w = tid >> 6, l = tid & 63;
  int lrow = l & 15, lk = l >> 4;
  f32x4 acc[2][4];
#pragma unroll
  for (int mt = 0; mt < 2; ++mt)
#pragma unroll
    for (int nt = 0; nt < 4; ++nt) acc[mt][nt] = (f32x4)0.0f;

  int arow = tid >> 1, akh = tid & 1;
  int brow = tid & 63, bkq = tid >> 6;
  int r_w = ((brow >> 4) << 8) + j0 + (brow & 15);   // gate*256 + j
  const float* wrow = (d ? Wb : Wf) + (size_t)r_w * 256;

  for (int kc = 0; kc < 8; ++kc) {
    int k0 = kc * 32;
    __syncthreads();
    {
      const float* ap = emb + (size_t)tok[arow] * 256 + k0 + akh * 16;
#pragma unroll
      for (int q = 0; q < 2; ++q) {
        float4 v0 = *(const float4*)(ap + q * 8);
        float4 v1 = *(const float4*)(ap + q * 8 + 4);
        uint4 pk;
        pk.x = pkh(v0.x, v0.y); pk.y = pkh(v0.z, v0.w);
        pk.z = pkh(v1.x, v1.y); pk.w = pkh(v1.z, v1.w);
        *(uint4*)&A_lds[arow][akh * 16 + q * 8] = pk;
      }
    }
    {
      float4 v0 = *(const float4*)(wrow + k0 + bkq * 8);
      float4 v1 = *(const float4*)(wrow + k0 + bkq * 8 + 4);
      uint4 pk;
      pk.x = pkh(v0.x, v0.y); pk.y = pkh(v0.z, v0.w);
      pk.z = pkh(v1.x, v1.y); pk.w = pkh(v1.z, v1.w);
      *(uint4*)&B_lds[brow][bkq * 8] = pk;
    }
    __syncthreads();
    half8 af[2], bf[4];
#pragma unroll
    for (int mt = 0; mt < 2; ++mt)
      af[mt] = *(const half8*)&A_lds[w * 32 + mt * 16 + lrow][lk * 8];
#pragma unroll
    for (int nt = 0; nt < 4; ++nt)
      bf[nt] = *(const half8*)&B_lds[nt * 16 + lrow][lk * 8];
#pragma unroll
    for (int mt = 0; mt < 2; ++mt)
#pragma unroll
      for (int nt = 0; nt < 4; ++nt)
        acc[mt][nt] = __builtin_amdgcn_mfma_f32_16x16x32_f16(af[mt], bf[nt], acc[mt][nt], 0, 0, 0);
  }
  float bias[4];
#pragma unroll
  for (int nt = 0; nt < 4; ++nt) {
    int rr = nt * 256 + j0 + lrow;
    bias[nt] = d ? (bihb[rr] + bhhb[rr]) : (bihf[rr] + bhhf[rr]);
  }
  __syncthreads();
#pragma unroll
  for (int mt = 0; mt < 2; ++mt)
#pragma unroll
    for (int r = 0; r < 4; ++r) {
      int row = w * 32 + mt * 16 + lk * 4 + r;
      uint2 pk;
      pk.x = (unsigned int)f2b(acc[mt][0][r] + bias[0]) |
             ((unsigned int)f2b(acc[mt][1][r] + bias[1]) << 16);
      pk.y = (unsigned int)f2b(acc[mt][2][r] + bias[2]) |
             ((unsigned int)f2b(acc[mt][3][r] + bias[3]) << 16);
      *(uint2*)&Xs[row][lrow * 4] = pk;
    }
  __syncthreads();
  int frow = tid >> 1, fh = tid & 1;
  int i = im * 128 + frow;
  int bb = i >> 8, tt = i & 255;
  size_t base = (((size_t)d * NT + tt) * NB + bb) * 1024 + (size_t)j0 * 4 + fh * 32;
#pragma unroll
  for (int q = 0; q < 4; ++q)
    *(uint4*)&X4[base + q * 8] = *(const uint4*)&Xs[frow][fh * 32 + q * 8];
}

// ---------------------------------------------------------------- lstm_scan
// 256 blocks = (d, b, p-half), 512 threads = (jj 0..127, group g 0..3).
// Thread kk range [g*32, g*32+32): 10 kk from LDS slab + 22 kk from regs.
// Per step: stage partner h-half (agent atomics, gated by partner flag),
// dot2s, partial-reduce, g0 finalizes 128 j's, publish own h-half + flag.
__global__ __launch_bounds__(512, 2) void lstm_scan(const uint4* __restrict__ WT,
                                                    const ushort4* __restrict__ X4,
                                                    const float* __restrict__ h0,
                                                    const float* __restrict__ c0,
                                                    u16* __restrict__ H,
                                                    unsigned int* __restrict__ slotb,
                                                    int* __restrict__ flags) {
  int bid = blockIdx.x;
  int d = bid >> 7, b = (bid >> 1) & 63, p = bid & 1;
  int pbid = bid ^ 1;
  int tid = threadIdx.x;
  int jj = tid & 127, g = tid >> 7;
  int jbase = p << 7;
  __shared__ uint4 wlds[5120];        // 80 KB slab: [g][r<10][jj]
  __shared__ uint4 h2s4[32];          // full h (256 f16)
  __shared__ float4 plds[3][128];     // 6 KB partials
  const uint4* Ws = WT + (size_t)d * 32768;  // [kk][j 0..255]
#pragma unroll
  for (int r = 0; r < 10; ++r)
    wlds[((g * 10 + r) << 7) | jj] = Ws[(size_t)(g * 32 + r) * 256 + jbase + jj];
  uint4 wreg[22];
#pragma unroll
  for (int r = 0; r < 22; ++r)
    wreg[r] = Ws[(size_t)(g * 32 + 10 + r) * 256 + jbase + jj];
  float c = 0.f;
  if (g == 0) c = c0[((size_t)d * NB + b) * 256 + jbase + jj];
  if (tid < 256) ((u16*)h2s4)[tid] = f2h(h0[((size_t)d * NB + b) * 256 + tid]);
  __syncthreads();
  for (int s = 0; s < NT; ++s) {
    int t = d ? (NT - 1 - s) : s;
    ushort4 xg = make_ushort4(0, 0, 0, 0);
    if (g == 0) xg = X4[(((size_t)d * NT + t) * NB + b) * 256 + jbase + jj];
    if (s > 0 && tid < 16) {
      if (tid == 0) {
        while (__hip_atomic_load(&flags[pbid], __ATOMIC_RELAXED,
                                 __HIP_MEMORY_SCOPE_AGENT) < s - 1) {}
      }
      asm volatile("" ::: "memory");   // wave-lockstep: lanes 1..15 resume after poll
      unsigned pb = (unsigned)(pbid * 2 + ((s - 1) & 1)) * 64 + tid * 4;
      uint4 hv;
      hv.x = __hip_atomic_load(&slotb[pb + 0], __ATOMIC_RELAXED, __HIP_MEMORY_SCOPE_AGENT);
      hv.y = __hip_atomic_load(&slotb[pb + 1], __ATOMIC_RELAXED, __HIP_MEMORY_SCOPE_AGENT);
      hv.z = __hip_atomic_load(&slotb[pb + 2], __ATOMIC_RELAXED, __HIP_MEMORY_SCOPE_AGENT);
      hv.w = __hip_atomic_load(&slotb[pb + 3], __ATOMIC_RELAXED, __HIP_MEMORY_SCOPE_AGENT);
      h2s4[((1 - p) << 4) + tid] = hv;
    }
    __syncthreads();                   // sync1: h_{s-1} complete in h2s4
    float ai = 0.f, af = 0.f, ag = 0.f, ao = 0.f;
    uint4 hv[8];
#pragma unroll
    for (int q = 0; q < 8; ++q) hv[q] = h2s4[(g << 3) + q];
    unsigned int hp[32];
#pragma unroll
    for (int q = 0; q < 8; ++q) {
      hp[q * 4 + 0] = hv[q].x; hp[q * 4 + 1] = hv[q].y;
      hp[q * 4 + 2] = hv[q].z; hp[q * 4 + 3] = hv[q].w;
    }
#pragma unroll
    for (int r = 0; r < 10; ++r) {
      uint4 wv = wlds[((g * 10 + r) << 7) | jj];
      ai = dot2h(wv.x, hp[r], ai); af = dot2h(wv.y, hp[r], af);
      ag = dot2h(wv.z, hp[r], ag); ao = dot2h(wv.w, hp[r], ao);
    }
#pragma unroll
    for (int r = 0; r < 22; ++r) {
      uint4 wv = wreg[r];
      ai = dot2h(wv.x, hp[10 + r], ai); af = dot2h(wv.y, hp[10 + r], af);
      ag = dot2h(wv.z, hp[10 + r], ag); ao = dot2h(wv.w, hp[10 + r], ao);
    }
    if (g) plds[g - 1][jj] = make_float4(ai, af, ag, ao);
    __syncthreads();                   // sync2: partials visible
    if (g == 0) {
      float4 p0 = plds[0][jj], p1 = plds[1][jj], p2 = plds[2][jj];
      ai += p0.x + p1.x + p2.x + b2f(xg.x);
      af += p0.y + p1.y + p2.y + b2f(xg.y);
      ag += p0.z + p1.z + p2.z + b2f(xg.z);
      ao += p0.w + p1.w + p2.w + b2f(xg.w);
      float ii = fsig(ai), ff = fsig(af), gg = ftanh(ag), oo = fsig(ao);
      c = ff * c + ii * gg;
      float h = oo * ftanh(c);
      u16 hu = f2h(h);
      ((u16*)h2s4)[jbase + jj] = hu;
      H[(((size_t)d * NB + b) * NT + t) * 256 + jbase + jj] = hu;
    }
    __syncthreads();                   // sync3: own half in h2s4
    if (tid < 16) {
      uint4 ho = h2s4[(p << 4) + tid];
      unsigned ob = (unsigned)(bid * 2 + (s & 1)) * 64 + tid * 4;
      __hip_atomic_store(&slotb[ob + 0], ho.x, __ATOMIC_RELAXED, __HIP_MEMORY_SCOPE_AGENT);
      __hip_atomic_store(&slotb[ob + 1], ho.y, __ATOMIC_RELAXED, __HIP_MEMORY_SCOPE_AGENT);
      __hip_atomic_store(&slotb[ob + 2], ho.z, __ATOMIC_RELAXED, __HIP_MEMORY_SCOPE_AGENT);
      __hip_atomic_store(&slotb[ob + 3], ho.w, __ATOMIC_RELAXED, __HIP_MEMORY_SCOPE_AGENT);
    }
    if (tid == 0)                      // release: waits wave-0's pushes (shared vmcnt)
      __hip_atomic_store(&flags[bid], s, __ATOMIC_RELEASE, __HIP_MEMORY_SCOPE_AGENT);
  }
}

// ---------------------------------------------------------------- feats
// (unchanged from round 10)
__global__ __launch_bounds__(384) void feats_kernel(const u16* __restrict__ H,
                                                    const unsigned int* __restrict__ WpH,
                                                    const float* __restrict__ bp,
                                                    float* __restrict__ FT) {
  __shared__ uint4 hbuf[32][65];
  __shared__ uint4 wbuf[64][12];
  int tid = threadIdx.x;
  int i0 = blockIdx.x * 32;
  for (int idx = tid; idx < 768; idx += 384) {
    int it = idx / 12, k = idx - it * 12;
    wbuf[it][k] = ((const uint4*)WpH)[k * 64 + it];
  }
  for (int idx = tid; idx < 2048; idx += 384) {
    int row = idx >> 6, c4 = idx & 63;
    int i = i0 + row;
    int b = i >> 8, t = i & 255;
    int dd = c4 >> 5, cc = c4 & 31;
    const uint4* hpg = (const uint4*)(H + (((size_t)dd * NB + b) * NT + t) * 256);
    hbuf[row][c4] = hpg[cc];
  }
  __syncthreads();
  int row = tid / 12, k = tid - row * 12;
  float s = 0.f;
#pragma unroll 8
  for (int it = 0; it < 64; ++it) {
    uint4 h4 = hbuf[row][it];
    uint4 w4 = wbuf[it][k];
    s = dot2h(h4.x, w4.x, s); s = dot2h(h4.y, w4.y, s);
    s = dot2h(h4.z, w4.z, s); s = dot2h(h4.w, w4.w, s);
  }
  int i = i0 + row;
  FT[(size_t)i * NKTAG + k] = s + bp[k];
}

// ---------------------------------------------------------------- viterbi
__global__ __launch_bounds__(64) void viterbi_kernel(const float* __restrict__ FT,
                                                     const float* __restrict__ trans,
                                                     const int* __restrict__ sent,
                                                     float* __restrict__ out) {
  int b = blockIdx.x, tid = threadIdx.x;
  __shared__ float trans_s[12][12];
  __shared__ float s_s[12];
  __shared__ unsigned char bp_s[256][12];
  __shared__ int path_s[256];
  for (int idx = tid; idx < 144; idx += 64) trans_s[idx / 12][idx % 12] = trans[idx];
  int cnt = 0;
#pragma unroll
  for (int q = 0; q < 4; ++q) cnt += (sent[b * NT + q * 64 + tid] > 0) ? 1 : 0;
  for (int off = 32; off; off >>= 1) cnt += __shfl_down(cnt, off);
  int len = __shfl(cnt, 0);
  if (tid < 12) s_s[tid] = (tid == START_TAG) ? 0.f : -10000.f;
  __syncthreads();
  for (int t = 0; t < NT; ++t) {
    float best = 0.f, f = 0.f;
    int barg = 0;
    if (tid < 12) {
      f = FT[((size_t)b * NT + t) * NKTAG + tid];
      best = s_s[0] + trans_s[tid][0];
      barg = 0;
#pragma unroll
      for (int fr = 1; fr < 12; ++fr) {
        float v = s_s[fr] + trans_s[tid][fr];
        if (v > best) { best = v; barg = fr; }
      }
    }
    __syncthreads();
    if (tid < 12) {
      s_s[tid] = best + f;
      bp_s[t][tid] = (unsigned char)barg;
    }
    __syncthreads();
  }
  if (tid == 0) {
    float bs = s_s[0];
    int bt = 0;
    for (int k = 1; k < 12; ++k)
      if (s_s[k] > bs) { bs = s_s[k]; bt = k; }
    out[NB * NT + b] = bs;
    int x = bt;
    for (int tt = NT - 1; tt >= 0; --tt) {
      path_s[tt] = x;
      int nxt = bp_s[tt][x];
      if (tt < len) x = nxt;
    }
  }
  __syncthreads();
#pragma unroll
  for (int q = 0; q < 4; ++q) {
    int t = q * 64 + tid;
    out[b * NT + t] = (t < len) ? (float)path_s[t] : -1.0f;
  }
}

// ---------------------------------------------------------------- launch
extern "C" void kernel_launch(void* const* d_in, const int* in_sizes, int n_in,
                              void* d_out, int out_size, void* d_ws, size_t ws_size,
                              hipStream_t stream) {
  (void)in_sizes; (void)n_in; (void)out_size; (void)ws_size;
  const int*   sent  = (const int*)d_in[0];
  const float* emb   = (const float*)d_in[2];
  const float* Wih_f = (const float*)d_in[3];
  const float* Whh_f = (const float*)d_in[4];
  const float* bih_f = (const float*)d_in[5];
  const float* bhh_f = (const float*)d_in[6];
  const float* Wih_b = (const float*)d_in[7];
  const float* Whh_b = (const float*)d_in[8];
  const float* bih_b = (const float*)d_in[9];
  const float* bhh_b = (const float*)d_in[10];
  const float* Wp    = (const float*)d_in[11];
  const float* bp    = (const float*)d_in[12];
  const float* trans = (const float*)d_in[13];
  const float* h0    = (const float*)d_in[14];
  const float* c0    = (const float*)d_in[15];
  float* out = (float*)d_out;

  char* w = (char*)d_ws;
  u16*   X4  = (u16*)w;                                      // 67108864 B
  uint4* WTH = (uint4*)(w + 67108864);                       //  1048576 B
  float* FT  = (float*)(w + 68157440);                       //   786432 B
  unsigned int* WpH = (unsigned int*)(w + 68943872);         //    12288 B
  u16*   H   = (u16*)(w + 68956160);                         // 16777216 B
  unsigned int* slotb = (unsigned int*)(w + 85733376);       //   131072 B
  int*   flags = (int*)(w + 85864448);                       //     1024 B

  hipMemsetAsync(flags, 0xFF, 1024, stream);                 // flags = -1 each call
  pack_whh<<<dim3(257), dim3(256), 0, stream>>>(Whh_f, Whh_b, Wp, WTH, WpH);
  gemm_x<<<dim3(32, 128), dim3(256), 0, stream>>>(sent, emb, Wih_f, Wih_b,
                                                  bih_f, bhh_f, bih_b, bhh_b, X4);
  lstm_scan<<<dim3(256), dim3(512), 0, stream>>>(WTH, (const ushort4*)X4, h0, c0,
                                                 H, slotb, flags);
  feats_kernel<<<dim3(512), dim3(384), 0, stream>>>(H, WpH, bp, FT);
  viterbi_kernel<<<dim3(64), dim3(64), 0, stream>>>(FT, trans, sent, out);
}